// Round 4
// baseline (324.312 us; speedup 1.0000x reference)
//
#include <hip/hip_runtime.h>

// Problem constants (reference: Q=2048, N=32768, D=512, C=100)
#define QN 2048
#define NN 32768
#define DD 512
#define CC 100
#define MAXTILES 356            // sum ceil(n_c/128) <= 256 + 100
#define MAXNP (MAXTILES * 128)  // 45568 max padded columns

typedef float f32x4 __attribute__((ext_vector_type(4)));
typedef __bf16 bf16x8 __attribute__((ext_vector_type(8)));
typedef unsigned short u16x8 __attribute__((ext_vector_type(8)));

// meta layout (int32 indices within first 4 KiB of ws)
#define M_HIST 0    // [100] class histogram
#define M_FILL 128  // [100] scatter fill counters
#define M_SEG 256   // [101] padded start column per class
#define M_TC 384    // [356] class of each 128-col tile
#define M_NT 768    // number of 128-col tiles
#define M_NCOL 769  // total padded columns

// ws byte offsets
#define OFF_X2 4096
#define OFF_DB2 16384
#define OFF_MIN 262144
#define OFF_XB (1u << 21)
#define OFF_DBS (1u << 22)

__device__ __forceinline__ unsigned short f2bf(float f) {
  unsigned u = __float_as_uint(f);
  unsigned r = 0x7FFFu + ((u >> 16) & 1u);  // round-to-nearest-even
  return (unsigned short)((u + r) >> 16);
}

typedef const __attribute__((address_space(1))) void* gptr_t;
typedef __attribute__((address_space(3))) void* lptr_t;
__device__ __forceinline__ void gload_lds16(const void* g, void* l) {
  __builtin_amdgcn_global_load_lds((gptr_t)g, (lptr_t)l, 16, 0, 0);
}

// ---- class histogram (LDS-local then one flush per block) ----
__global__ void k_hist(const int* __restrict__ labels, int* __restrict__ meta) {
  __shared__ int h[CC];
  int t = threadIdx.x;
  if (t < CC) h[t] = 0;
  __syncthreads();
#pragma unroll
  for (int i = 0; i < 4; ++i) {
    int n = blockIdx.x * 1024 + i * 256 + t;
    atomicAdd(&h[labels[n]], 1);
  }
  __syncthreads();
  if (t < CC) atomicAdd(&meta[M_HIST + t], h[t]);
}

// ---- scan over 100 classes (serial part runs on LDS, writes parallel) ----
__global__ void k_scan(int* __restrict__ meta) {
  __shared__ int h[CC], seg[CC + 1], tile0[CC];
  int t = threadIdx.x;
  for (int c = t; c < CC; c += 128) h[c] = meta[M_HIST + c];
  __syncthreads();
  if (t == 0) {
    int col = 0, nt = 0;
    for (int c = 0; c < CC; ++c) {
      seg[c] = col;
      tile0[c] = nt;
      int tiles = (h[c] + 127) >> 7;
      nt += tiles;
      col += tiles << 7;
    }
    seg[CC] = col;
    meta[M_NT] = nt;
    meta[M_NCOL] = col;
    meta[M_SEG + CC] = col;
  }
  __syncthreads();
  for (int c = t; c < CC; c += 128) {
    meta[M_SEG + c] = seg[c];
    int tiles = (h[c] + 127) >> 7;
    int t0 = tile0[c];
    for (int i = 0; i < tiles; ++i) meta[M_TC + t0 + i] = c;
  }
}

// ---- x: fp32 -> bf16 + row sumsq. One wave per row. ----
__global__ void k_prep_x(const float* __restrict__ x, unsigned short* __restrict__ xb,
                         float* __restrict__ x2) {
  int w = threadIdx.x >> 6, lane = threadIdx.x & 63;
  int q = blockIdx.x * 4 + w;
  const float4* row = (const float4*)(x + (size_t)q * DD);
  float4 v0 = row[lane * 2];
  float4 v1 = row[lane * 2 + 1];
  float s = v0.x * v0.x + v0.y * v0.y + v0.z * v0.z + v0.w * v0.w +
            v1.x * v1.x + v1.y * v1.y + v1.z * v1.z + v1.w * v1.w;
  u16x8 o;
  o[0] = f2bf(v0.x); o[1] = f2bf(v0.y); o[2] = f2bf(v0.z); o[3] = f2bf(v0.w);
  o[4] = f2bf(v1.x); o[5] = f2bf(v1.y); o[6] = f2bf(v1.z); o[7] = f2bf(v1.w);
  ((u16x8*)(xb + (size_t)q * DD))[lane] = o;
#pragma unroll
  for (int m = 32; m; m >>= 1) s += __shfl_xor(s, m);
  if (lane == 0) x2[q] = s;
}

// ---- db: scatter row n -> sorted padded position, fp32 -> bf16, sumsq ----
__global__ void k_scatter(const float* __restrict__ db, const int* __restrict__ labels,
                          int* __restrict__ meta, unsigned short* __restrict__ dbs,
                          float* __restrict__ db2s) {
  int w = threadIdx.x >> 6, lane = threadIdx.x & 63;
  int n = blockIdx.x * 4 + w;
  int c = labels[n];
  int pos = 0;
  if (lane == 0) pos = meta[M_SEG + c] + atomicAdd(&meta[M_FILL + c], 1);
  pos = __shfl(pos, 0);
  const float4* row = (const float4*)(db + (size_t)n * DD);
  float4 v0 = row[lane * 2];
  float4 v1 = row[lane * 2 + 1];
  float s = v0.x * v0.x + v0.y * v0.y + v0.z * v0.z + v0.w * v0.w +
            v1.x * v1.x + v1.y * v1.y + v1.z * v1.z + v1.w * v1.w;
  u16x8 o;
  o[0] = f2bf(v0.x); o[1] = f2bf(v0.y); o[2] = f2bf(v0.z); o[3] = f2bf(v0.w);
  o[4] = f2bf(v1.x); o[5] = f2bf(v1.y); o[6] = f2bf(v1.z); o[7] = f2bf(v1.w);
  ((u16x8*)(dbs + (size_t)pos * DD))[lane] = o;
#pragma unroll
  for (int m = 32; m; m >>= 1) s += __shfl_xor(s, m);
  if (lane == 0) db2s[pos] = s;
}

// ---- fill padded slots: zero rows, db2 = +inf (never wins the min) ----
__global__ void k_pad(const int* __restrict__ meta, unsigned short* __restrict__ dbs,
                      float* __restrict__ db2s) {
  int w = threadIdx.x >> 6, lane = threadIdx.x & 63;
  int p = blockIdx.x * 4 + w;
  if (p >= meta[M_NCOL]) return;
  int c = meta[M_TC + (p >> 7)];
  if (p - meta[M_SEG + c] < meta[M_HIST + c]) return;  // real row, written by scatter
  u16x8 z = {0, 0, 0, 0, 0, 0, 0, 0};
  ((u16x8*)(dbs + (size_t)p * DD))[lane] = z;
  if (lane == 0) db2s[p] = __builtin_inff();
}

__global__ void k_initmin(unsigned* __restrict__ mb) {
  int i = blockIdx.x * 256 + threadIdx.x;
  if (i < QN * CC) mb[i] = 0x7F800000u;  // +inf bits
}

// ---- fused bf16 MFMA GEMM + per-class row-min ----
// 128x128 tile, BK=64, double-buffered LDS (T3-minimum 2-phase: issue stage
// for tile t+1 BEFORE ds_read+MFMA of tile t, single drain after compute).
// LDS XOR-swizzle (slot ^= row&7) with pre-swizzled global source (rule 21).
// XCD-chunked block remap so the 16 M-blocks sharing a B-tile colocate.
__launch_bounds__(256)
__global__ void k_gemm(const unsigned short* __restrict__ xb,
                       const unsigned short* __restrict__ dbs,
                       const float* __restrict__ x2, const float* __restrict__ db2s,
                       const int* __restrict__ meta, unsigned* __restrict__ minbits) {
  // XCD-aware bijective remap: 5696 blocks, 8 XCDs, 712 per XCD chunk.
  int flat = blockIdx.y * 16 + blockIdx.x;
  int swz = (flat & 7) * (16 * MAXTILES / 8) + (flat >> 3);
  int tq = swz & 15, tn = swz >> 4;
  if (tn >= meta[M_NT]) return;
  int cls = meta[M_TC + tn];

  __shared__ __align__(16) unsigned short As[2][128 * 64];
  __shared__ __align__(16) unsigned short Bs[2][128 * 64];

  int t = threadIdx.x;
  int lane = t & 63;
  int wid = t >> 6;
  int wm = wid >> 1, wn = wid & 1;  // 2x2 waves of 64x64
  int cl = lane & 15, g = lane >> 4;

  f32x4 acc[4][4];
#pragma unroll
  for (int m = 0; m < 4; ++m)
#pragma unroll
    for (int n = 0; n < 4; ++n) acc[m][n] = (f32x4){0.f, 0.f, 0.f, 0.f};

  // Staging: pass j writes LDS rows j*32+(t>>3), slot t&7 (linear dest for
  // global_load_lds). Source col-slot pre-swizzled: S_global = (t&7)^((t>>3)&7)
  // so that LDS (R,S) holds global (R, S^(R&7)).
  const unsigned short* Ab =
      xb + ((size_t)tq * 128 + (t >> 3)) * DD + (size_t)(((t & 7) ^ ((t >> 3) & 7)) * 8);
  const unsigned short* Bb =
      dbs + ((size_t)tn * 128 + (t >> 3)) * DD + (size_t)(((t & 7) ^ ((t >> 3) & 7)) * 8);

  auto stage = [&](int buf, int k0) {
#pragma unroll
    for (int j = 0; j < 4; ++j) {
      gload_lds16(Ab + (size_t)j * 32 * DD + k0, &As[buf][j * 2048 + t * 8]);
      gload_lds16(Bb + (size_t)j * 32 * DD + k0, &Bs[buf][j * 2048 + t * 8]);
    }
  };

  stage(0, 0);
  asm volatile("s_waitcnt vmcnt(0)" ::: "memory");
  __syncthreads();

  for (int kt = 0; kt < DD / 64; ++kt) {
    int cur = kt & 1;
    if (kt < DD / 64 - 1) stage(cur ^ 1, (kt + 1) * 64);  // in flight during compute

    const unsigned short* Ac = &As[cur][0];
    const unsigned short* Bc = &Bs[cur][0];
#pragma unroll
    for (int kk = 0; kk < 2; ++kk) {
      bf16x8 af[4], bfb[4];
#pragma unroll
      for (int m = 0; m < 4; ++m) {
        int R = wm * 64 + m * 16 + cl;
        int S = (kk * 4 + g) ^ (cl & 7);  // swizzled read
        af[m] = *(const bf16x8*)(Ac + R * 64 + S * 8);
      }
#pragma unroll
      for (int n = 0; n < 4; ++n) {
        int R = wn * 64 + n * 16 + cl;
        int S = (kk * 4 + g) ^ (cl & 7);
        bfb[n] = *(const bf16x8*)(Bc + R * 64 + S * 8);
      }
#pragma unroll
      for (int m = 0; m < 4; ++m)
#pragma unroll
        for (int n = 0; n < 4; ++n)
          acc[m][n] = __builtin_amdgcn_mfma_f32_16x16x32_bf16(af[m], bfb[n], acc[m][n], 0, 0, 0);
    }
    __syncthreads();  // implicit vmcnt(0): next buffer ready; cur safe to overwrite
  }

  // Epilogue: whole block is one class. d2 = x2[q] + min_n(db2[n] - 2*dot).
  float db2v[4];
#pragma unroll
  for (int n = 0; n < 4; ++n) db2v[n] = db2s[tn * 128 + wn * 64 + n * 16 + cl];

#pragma unroll
  for (int m = 0; m < 4; ++m) {
    int rowb = tq * 128 + wm * 64 + m * 16 + g * 4;
#pragma unroll
    for (int r = 0; r < 4; ++r) {
      float v = db2v[0] - 2.0f * acc[m][0][r];
      v = fminf(v, db2v[1] - 2.0f * acc[m][1][r]);
      v = fminf(v, db2v[2] - 2.0f * acc[m][2][r]);
      v = fminf(v, db2v[3] - 2.0f * acc[m][3][r]);
#pragma unroll
      for (int s = 1; s < 16; s <<= 1) v = fminf(v, __shfl_xor(v, s));
      if (cl == 0) {
        float d = sqrtf(fmaxf(x2[rowb + r] + v, 0.0f));
        atomicMin(minbits + (size_t)(rowb + r) * CC + cls, __float_as_uint(d));
      }
    }
  }
}

__global__ void k_final(const unsigned* __restrict__ mb, float* __restrict__ out) {
  int i = blockIdx.x * 256 + threadIdx.x;
  if (i < QN * CC) out[i] = -__uint_as_float(mb[i]);
}

extern "C" void kernel_launch(void* const* d_in, const int* in_sizes, int n_in,
                              void* d_out, int out_size, void* d_ws, size_t ws_size,
                              hipStream_t stream) {
  (void)in_sizes; (void)n_in; (void)out_size; (void)ws_size;
  const float* x = (const float*)d_in[0];
  const float* db = (const float*)d_in[1];
  const int* labels = (const int*)d_in[2];

  char* ws = (char*)d_ws;
  int* meta = (int*)ws;
  float* x2 = (float*)(ws + OFF_X2);
  float* db2s = (float*)(ws + OFF_DB2);
  unsigned* minbits = (unsigned*)(ws + OFF_MIN);
  unsigned short* xb = (unsigned short*)(ws + OFF_XB);
  unsigned short* dbs = (unsigned short*)(ws + OFF_DBS);

  hipMemsetAsync(ws, 0, 4096, stream);
  k_hist<<<NN / 1024, 256, 0, stream>>>(labels, meta);
  k_scan<<<1, 128, 0, stream>>>(meta);
  k_prep_x<<<QN / 4, 256, 0, stream>>>(x, xb, x2);
  k_scatter<<<NN / 4, 256, 0, stream>>>(db, labels, meta, dbs, db2s);
  k_pad<<<MAXNP / 4, 256, 0, stream>>>(meta, dbs, db2s);
  k_initmin<<<(QN * CC + 255) / 256, 256, 0, stream>>>(minbits);
  k_gemm<<<dim3(16, MAXTILES), 256, 0, stream>>>(xb, dbs, x2, db2s, meta, minbits);
  k_final<<<(QN * CC + 255) / 256, 256, 0, stream>>>(minbits, (float*)d_out);
}

// Round 5
// 313.354 us; speedup vs baseline: 1.0350x; 1.0350x over previous
//
#include <hip/hip_runtime.h>

// Problem constants (reference: Q=2048, N=32768, D=512, C=100)
#define QN 2048
#define NN 32768
#define DD 512
#define CC 100
#define MAXTILES 356            // sum ceil(n_c/128) <= 256 + 100
#define MAXNP (MAXTILES * 128)  // 45568 max padded columns
#define NT256 (MAXTILES / 2)    // 178 max 256-col tiles

typedef float f32x4 __attribute__((ext_vector_type(4)));
typedef __bf16 bf16x8 __attribute__((ext_vector_type(8)));
typedef unsigned short u16x8 __attribute__((ext_vector_type(8)));

// meta layout (int32 indices within first 4 KiB of ws)
#define M_HIST 0    // [100] class histogram
#define M_FILL 128  // [100] scatter fill counters
#define M_SEG 256   // [101] padded start column per class
#define M_TC 384    // [356] class of each 128-col tile (0 beyond NT via memset)
#define M_NT 768    // number of 128-col tiles
#define M_NCOL 769  // total padded columns, rounded UP to 256

// ws byte offsets
#define OFF_X2 4096
#define OFF_DB2 16384
#define OFF_MIN 262144
#define OFF_XB (1u << 21)
#define OFF_DBS (1u << 22)

__device__ __forceinline__ unsigned short f2bf(float f) {
  unsigned u = __float_as_uint(f);
  unsigned r = 0x7FFFu + ((u >> 16) & 1u);  // round-to-nearest-even
  return (unsigned short)((u + r) >> 16);
}

typedef const __attribute__((address_space(1))) void* gptr_t;
typedef __attribute__((address_space(3))) void* lptr_t;
__device__ __forceinline__ void gload_lds16(const void* g, void* l) {
  __builtin_amdgcn_global_load_lds((gptr_t)g, (lptr_t)l, 16, 0, 0);
}

// ---- histogram + scan fused (single block; LDS hist, serial scan) ----
__global__ void k_meta(const int* __restrict__ labels, int* __restrict__ meta) {
  __shared__ int h[CC], seg[CC], t0[CC];
  int t = threadIdx.x;  // 1024 threads
  if (t < CC) h[t] = 0;
  __syncthreads();
  for (int i = t; i < NN; i += 1024) atomicAdd(&h[labels[i]], 1);
  __syncthreads();
  if (t == 0) {
    int col = 0, nt = 0;
    for (int c = 0; c < CC; ++c) {
      seg[c] = col;
      t0[c] = nt;
      int tiles = (h[c] + 127) >> 7;
      nt += tiles;
      col += tiles << 7;
    }
    meta[M_NT] = nt;
    meta[M_NCOL] = ((nt + 1) >> 1) << 8;  // pad to 256-col multiple
    meta[M_SEG + CC] = col;
  }
  __syncthreads();
  if (t < CC) {
    meta[M_HIST + t] = h[t];
    meta[M_SEG + t] = seg[t];
    int tiles = (h[t] + 127) >> 7;
    for (int i = 0; i < tiles; ++i) meta[M_TC + t0[t] + i] = t;
  }
}

// ---- x: fp32 -> bf16 + row sumsq. One wave per row. ----
__global__ void k_prep_x(const float* __restrict__ x, unsigned short* __restrict__ xb,
                         float* __restrict__ x2) {
  int w = threadIdx.x >> 6, lane = threadIdx.x & 63;
  int q = blockIdx.x * 4 + w;
  const float4* row = (const float4*)(x + (size_t)q * DD);
  float4 v0 = row[lane * 2];
  float4 v1 = row[lane * 2 + 1];
  float s = v0.x * v0.x + v0.y * v0.y + v0.z * v0.z + v0.w * v0.w +
            v1.x * v1.x + v1.y * v1.y + v1.z * v1.z + v1.w * v1.w;
  u16x8 o;
  o[0] = f2bf(v0.x); o[1] = f2bf(v0.y); o[2] = f2bf(v0.z); o[3] = f2bf(v0.w);
  o[4] = f2bf(v1.x); o[5] = f2bf(v1.y); o[6] = f2bf(v1.z); o[7] = f2bf(v1.w);
  ((u16x8*)(xb + (size_t)q * DD))[lane] = o;
#pragma unroll
  for (int m = 32; m; m >>= 1) s += __shfl_xor(s, m);
  if (lane == 0) x2[q] = s;
}

// ---- scatter + pad-fill + min-init, one kernel (independent branches) ----
__global__ void k_spi(const float* __restrict__ db, const int* __restrict__ labels,
                      int* __restrict__ meta, unsigned short* __restrict__ dbs,
                      float* __restrict__ db2s, unsigned* __restrict__ mb) {
  int b = blockIdx.x, t = threadIdx.x;
  if (b < (QN * CC) / 256) mb[b * 256 + t] = 0x7F800000u;  // +inf bits (800 blocks exact)
  int w = t >> 6, lane = t & 63;
  if (b < NN / 4) {
    int n = b * 4 + w;
    int c = labels[n];
    int pos = 0;
    if (lane == 0) pos = meta[M_SEG + c] + atomicAdd(&meta[M_FILL + c], 1);
    pos = __shfl(pos, 0);
    const float4* row = (const float4*)(db + (size_t)n * DD);
    float4 v0 = row[lane * 2];
    float4 v1 = row[lane * 2 + 1];
    float s = v0.x * v0.x + v0.y * v0.y + v0.z * v0.z + v0.w * v0.w +
              v1.x * v1.x + v1.y * v1.y + v1.z * v1.z + v1.w * v1.w;
    u16x8 o;
    o[0] = f2bf(v0.x); o[1] = f2bf(v0.y); o[2] = f2bf(v0.z); o[3] = f2bf(v0.w);
    o[4] = f2bf(v1.x); o[5] = f2bf(v1.y); o[6] = f2bf(v1.z); o[7] = f2bf(v1.w);
    ((u16x8*)(dbs + (size_t)pos * DD))[lane] = o;
#pragma unroll
    for (int m = 32; m; m >>= 1) s += __shfl_xor(s, m);
    if (lane == 0) db2s[pos] = s;
  } else {
    int p = (b - NN / 4) * 4 + w;
    if (p >= meta[M_NCOL]) return;
    int c = meta[M_TC + (p >> 7)];
    if (p - meta[M_SEG + c] < meta[M_HIST + c]) return;  // real row, written by scatter
    u16x8 z = {0, 0, 0, 0, 0, 0, 0, 0};
    ((u16x8*)(dbs + (size_t)p * DD))[lane] = z;
    if (lane == 0) db2s[p] = __builtin_inff();
  }
}

// ---- fused bf16 MFMA GEMM + per-class row-min ----
// 256x256 tile, BK=32, 8 waves (2M x 4N), 4 LDS K-tile buffers (128 KiB).
// Counted-vmcnt pipeline (T3+T4): raw s_barrier, vmcnt(8) steady state
// (tiles t+1,t+2 stay in flight), stage tile t+3 into the buffer freed at
// t-1. LDS XOR-swizzle S^=( R>>1)&3 on 16B granules (2-way = free), with
// inverse-permuted global source (rule 21). Two 16-MFMA setprio clusters
// per K-tile (T5). XCD-chunked block remap (T1).
__launch_bounds__(512, 2)
__global__ void k_gemm(const unsigned short* __restrict__ xb,
                       const unsigned short* __restrict__ dbs,
                       const float* __restrict__ x2, const float* __restrict__ db2s,
                       const int* __restrict__ meta, unsigned* __restrict__ minbits) {
  // 8 x 178 = 1424 blocks; 178 per XCD chunk (bijective).
  int flat = blockIdx.y * 8 + blockIdx.x;
  int swz = (flat & 7) * NT256 + (flat >> 3);
  int tq = swz & 7, tn = swz >> 3;
  int nt = meta[M_NT];
  if (tn >= ((nt + 1) >> 1)) return;

  __shared__ __align__(16) unsigned short lds[4][2][256 * 32];  // 128 KiB

  int t = threadIdx.x;
  int lane = t & 63;
  int wid = t >> 6;
  int wm = wid >> 2, wn = wid & 3;  // 2M x 4N waves; per-wave out = 128 x 64
  int cl = lane & 15, g = lane >> 4;

  // staging source: thread t covers LDS (row j*128 + (t>>2), slot t&3);
  // global granule = slot ^ ((row>>1)&3) = (t&3) ^ ((t>>3)&3)  [j*128 even*]
  int gsrc = (t & 3) ^ ((t >> 3) & 3);
  const unsigned short* Ag = xb + ((size_t)tq * 256 + (t >> 2)) * DD + gsrc * 8;
  const unsigned short* Bg = dbs + ((size_t)tn * 256 + (t >> 2)) * DD + gsrc * 8;

  auto stage = [&](int buf, int tile) {
    int k0 = tile * 32;
#pragma unroll
    for (int j = 0; j < 2; ++j) {
      gload_lds16(Ag + (size_t)j * 128 * DD + k0, &lds[buf][0][j * 4096 + t * 8]);
      gload_lds16(Bg + (size_t)j * 128 * DD + k0, &lds[buf][1][j * 4096 + t * 8]);
    }
  };

  // per-lane LDS read offsets (shorts), swizzled: S_phys = g ^ ((R>>1)&3)
  int offA[8], offB[4];
#pragma unroll
  for (int m = 0; m < 8; ++m) {
    int R = wm * 128 + m * 16 + cl;
    offA[m] = R * 32 + ((g ^ ((R >> 1) & 3)) * 8);
  }
#pragma unroll
  for (int n = 0; n < 4; ++n) {
    int R = wn * 64 + n * 16 + cl;
    offB[n] = R * 32 + ((g ^ ((R >> 1) & 3)) * 8);
  }

  f32x4 acc[8][4];
#pragma unroll
  for (int m = 0; m < 8; ++m)
#pragma unroll
    for (int n = 0; n < 4; ++n) acc[m][n] = (f32x4){0.f, 0.f, 0.f, 0.f};

  const int NK = DD / 32;  // 16
  stage(0, 0);
  stage(1, 1);
  stage(2, 2);

  for (int kt = 0; kt < NK; ++kt) {
    // counted waitcnt: tile kt landed; tiles kt+1, kt+2 may stay in flight
    if (kt < NK - 2)
      asm volatile("s_waitcnt vmcnt(8)" ::: "memory");
    else if (kt == NK - 2)
      asm volatile("s_waitcnt vmcnt(4)" ::: "memory");
    else
      asm volatile("s_waitcnt vmcnt(0)" ::: "memory");
    __builtin_amdgcn_s_barrier();
    __builtin_amdgcn_sched_barrier(0);

    if (kt + 3 < NK) stage((kt + 3) & 3, kt + 3);  // buffer freed at kt-1

    const unsigned short* A_ = &lds[kt & 3][0][0];
    const unsigned short* B_ = &lds[kt & 3][1][0];

    bf16x8 b0[4], a0[4];
#pragma unroll
    for (int n = 0; n < 4; ++n) b0[n] = *(const bf16x8*)(B_ + offB[n]);
#pragma unroll
    for (int m = 0; m < 4; ++m) a0[m] = *(const bf16x8*)(A_ + offA[m]);
    asm volatile("s_waitcnt lgkmcnt(0)" ::: "memory");
    __builtin_amdgcn_sched_barrier(0);
    __builtin_amdgcn_s_setprio(1);
#pragma unroll
    for (int m = 0; m < 4; ++m)
#pragma unroll
      for (int n = 0; n < 4; ++n)
        acc[m][n] = __builtin_amdgcn_mfma_f32_16x16x32_bf16(a0[m], b0[n], acc[m][n], 0, 0, 0);
    __builtin_amdgcn_s_setprio(0);

    bf16x8 a1[4];
#pragma unroll
    for (int m = 0; m < 4; ++m) a1[m] = *(const bf16x8*)(A_ + offA[4 + m]);
    asm volatile("s_waitcnt lgkmcnt(0)" ::: "memory");
    __builtin_amdgcn_sched_barrier(0);
    __builtin_amdgcn_s_setprio(1);
#pragma unroll
    for (int m = 0; m < 4; ++m)
#pragma unroll
      for (int n = 0; n < 4; ++n)
        acc[4 + m][n] = __builtin_amdgcn_mfma_f32_16x16x32_bf16(a1[m], b0[n], acc[4 + m][n], 0, 0, 0);
    __builtin_amdgcn_s_setprio(0);
  }

  // Epilogue: each wave's 64 cols lie in one 128-half => single class.
  int cls = meta[M_TC + tn * 2 + (wn >> 1)];
  float db2v[4];
#pragma unroll
  for (int n = 0; n < 4; ++n) db2v[n] = db2s[tn * 256 + wn * 64 + n * 16 + cl];

#pragma unroll
  for (int m = 0; m < 8; ++m) {
    int rowb = tq * 256 + wm * 128 + m * 16 + g * 4;
#pragma unroll
    for (int r = 0; r < 4; ++r) {
      float v = db2v[0] - 2.0f * acc[m][0][r];
      v = fminf(v, db2v[1] - 2.0f * acc[m][1][r]);
      v = fminf(v, db2v[2] - 2.0f * acc[m][2][r]);
      v = fminf(v, db2v[3] - 2.0f * acc[m][3][r]);
#pragma unroll
      for (int s = 1; s < 16; s <<= 1) v = fminf(v, __shfl_xor(v, s));
      if (cl == 0) {
        float d = sqrtf(fmaxf(x2[rowb + r] + v, 0.0f));
        atomicMin(minbits + (size_t)(rowb + r) * CC + cls, __float_as_uint(d));
      }
    }
  }
}

__global__ void k_final(const unsigned* __restrict__ mb, float* __restrict__ out) {
  int i = blockIdx.x * 256 + threadIdx.x;
  if (i < QN * CC) out[i] = -__uint_as_float(mb[i]);
}

extern "C" void kernel_launch(void* const* d_in, const int* in_sizes, int n_in,
                              void* d_out, int out_size, void* d_ws, size_t ws_size,
                              hipStream_t stream) {
  (void)in_sizes; (void)n_in; (void)out_size; (void)ws_size;
  const float* x = (const float*)d_in[0];
  const float* db = (const float*)d_in[1];
  const int* labels = (const int*)d_in[2];

  char* ws = (char*)d_ws;
  int* meta = (int*)ws;
  float* x2 = (float*)(ws + OFF_X2);
  float* db2s = (float*)(ws + OFF_DB2);
  unsigned* minbits = (unsigned*)(ws + OFF_MIN);
  unsigned short* xb = (unsigned short*)(ws + OFF_XB);
  unsigned short* dbs = (unsigned short*)(ws + OFF_DBS);

  hipMemsetAsync(ws, 0, 4096, stream);
  k_meta<<<1, 1024, 0, stream>>>(labels, meta);
  k_prep_x<<<QN / 4, 256, 0, stream>>>(x, xb, x2);
  k_spi<<<NN / 4 + MAXNP / 4, 256, 0, stream>>>(db, labels, meta, dbs, db2s, minbits);
  k_gemm<<<dim3(8, NT256), 512, 0, stream>>>(xb, dbs, x2, db2s, meta, minbits);
  k_final<<<(QN * CC + 255) / 256, 256, 0, stream>>>(minbits, (float*)d_out);
}